// Round 6
// baseline (352.076 us; speedup 1.0000x reference)
//
#include <hip/hip_runtime.h>
#include <cstdint>
#include <cstddef>

// Problem constants (from reference): N=16384, D=256.
#define NV 16384
#define DD 256
#define MBLK 128   // k_mis vertices per sequential step (2 per lane)
#define PCAP 7
#define HROW 24    // u16 slots per vertex in hi_g: [0]=count, [1..23]=higher nbrs

// ---------------------------------------------------------------------------
// K_prep (parallel, one pass over nbr): per vertex v emit
//  - pend_g[v] (uint2): in-128-block lower neighbors as BYTE offsets (0..126)
//      x = count(8b) | e0<<8 | e1<<16 | e2<<24 ; y = e3 | e4<<8 | e5<<16 | e6<<24
//  - hi_g[v*HROW..]: [count, up to 23 higher-neighbor vertex ids] (u16)
// ---------------------------------------------------------------------------
__global__ __launch_bounds__(256)
void k_prep(const int* __restrict__ nbr, const int* __restrict__ deg,
            int maxdeg, int n, uint2* __restrict__ pend_g,
            unsigned short* __restrict__ hi_g)
{
    int v = blockIdx.x * 256 + threadIdx.x;
    if (v >= n) return;
    const int b  = v & ~(MBLK - 1);
    const int dv = deg[v];
    const int* __restrict__ row = nbr + (size_t)v * (size_t)maxdeg;
    unsigned short* __restrict__ hrow = hi_g + (size_t)v * HROW;
    unsigned px = 0, py = 0;
    int cnt = 0, hic = 0;
    for (int k = 0; k < dv; ++k) {
        int j = row[k];
        if (j > v) {
            if (hic < HROW - 1) hrow[1 + hic] = (unsigned short)j;
            ++hic;
        } else if (j >= b) {
            unsigned off = (unsigned)(j - b);          // 0..126
            if (cnt < 3)      px |= off << (8 * (cnt + 1));
            else if (cnt < 7) py |= off << (8 * (cnt - 3));
            ++cnt;
        }
    }
    hrow[0] = (unsigned short)hic;
    px |= (unsigned)(cnt > 255 ? 255 : cnt);
    pend_g[v] = make_uint2(px, py);
}

// ---------------------------------------------------------------------------
// K_mis: lexicographic greedy MIS, SINGLE WAVE (64 lanes), zero barriers.
// st: 0=unknown, 1=head, 2=nonhead in LDS; all DS ops ordered within the wave.
// 128 blocks of 128 vertices (2 per lane) processed sequentially; heads push
// st=2 to higher neighbors from register-resident hi lists. Pass-exit via
// __ballot. Global state (pend/hi/deg) prefetched 2 blocks ahead into named
// triple buffers (A/B/C) - no runtime-indexed register arrays.
// ---------------------------------------------------------------------------
#define PUSH1(word, sh, k, HIC) if ((k) < (HIC)) st[((word) >> (sh)) & 0xffffu] = 2;

#define DECIDE(MY, V, PD, HA, HB, HC, DG, B) do {                               \
    int _s = st[(V)];                                                           \
    if (_s != 0) { (MY) = 2; }                                                  \
    else {                                                                      \
        const unsigned _px = (PD).x, _py = (PD).y;                              \
        const int _np = _px & 0xFF;                                             \
        bool _anyH = false; int _undec = 0;                                     \
        if (_np <= PCAP) {                                                      \
            if (_np > 0) { int q = st[(B) + ((_px >> 8) & 0xFF)];  _anyH |= (q==1); _undec += (q==0); } \
            if (_np > 1) { int q = st[(B) + ((_px >> 16) & 0xFF)]; _anyH |= (q==1); _undec += (q==0); } \
            if (_np > 2) { int q = st[(B) + (_px >> 24)];          _anyH |= (q==1); _undec += (q==0); } \
            if (_np > 3) { int q = st[(B) + (_py & 0xFF)];         _anyH |= (q==1); _undec += (q==0); } \
            if (_np > 4) { int q = st[(B) + ((_py >> 8) & 0xFF)];  _anyH |= (q==1); _undec += (q==0); } \
            if (_np > 5) { int q = st[(B) + ((_py >> 16) & 0xFF)]; _anyH |= (q==1); _undec += (q==0); } \
            if (_np > 6) { int q = st[(B) + (_py >> 24)];          _anyH |= (q==1); _undec += (q==0); } \
        } else {                                                                \
            const int* _row = nbr + (size_t)(V) * (size_t)maxdeg;               \
            for (int _k = 0; _k < (DG); ++_k) { int _j = _row[_k];              \
                if (_j >= (B) && _j < (V)) { int q = st[_j]; _anyH |= (q==1); _undec += (q==0); } } \
        }                                                                       \
        if (_anyH) { (MY) = 2; }                                                \
        else if (_undec == 0) {                                                 \
            (MY) = 1; st[(V)] = 1;                                              \
            const int _hic = (int)((HA).x & 0xffffu);                           \
            if (_hic <= HROW - 1) {                                             \
                PUSH1((HA).x,16, 0,_hic) PUSH1((HA).y, 0, 1,_hic) PUSH1((HA).y,16, 2,_hic) \
                PUSH1((HA).z, 0, 3,_hic) PUSH1((HA).z,16, 4,_hic) PUSH1((HA).w, 0, 5,_hic) \
                PUSH1((HA).w,16, 6,_hic)                                        \
                PUSH1((HB).x, 0, 7,_hic) PUSH1((HB).x,16, 8,_hic) PUSH1((HB).y, 0, 9,_hic) \
                PUSH1((HB).y,16,10,_hic) PUSH1((HB).z, 0,11,_hic) PUSH1((HB).z,16,12,_hic) \
                PUSH1((HB).w, 0,13,_hic) PUSH1((HB).w,16,14,_hic)               \
                PUSH1((HC).x, 0,15,_hic) PUSH1((HC).x,16,16,_hic) PUSH1((HC).y, 0,17,_hic) \
                PUSH1((HC).y,16,18,_hic) PUSH1((HC).z, 0,19,_hic) PUSH1((HC).z,16,20,_hic) \
                PUSH1((HC).w, 0,21,_hic) PUSH1((HC).w,16,22,_hic)               \
            } else {                                                            \
                const int* _row = nbr + (size_t)(V) * (size_t)maxdeg;           \
                for (int _k = 0; _k < (DG); ++_k) { int _j = _row[_k]; if (_j > (V)) st[_j] = 2; } \
            }                                                                   \
        }                                                                       \
    }                                                                           \
} while (0)

#define DECLB(S)                                                                \
    uint2 pd##S##0 = make_uint2(0,0), pd##S##1 = make_uint2(0,0);               \
    uint4 ha##S##0 = make_uint4(0,0,0,0), hb##S##0 = ha##S##0, hc##S##0 = ha##S##0; \
    uint4 ha##S##1 = ha##S##0, hb##S##1 = ha##S##0, hc##S##1 = ha##S##0;        \
    int dg##S##0 = 0, dg##S##1 = 0;

#define LOADB(S, BB) do { const int _lb = (BB);                                 \
    if (_lb < n) { int _v0 = _lb + lane, _v1 = _lb + 64 + lane;                 \
        pd##S##0 = pend_g[_v0]; pd##S##1 = pend_g[_v1];                         \
        const uint4* _h0 = (const uint4*)(hi_g + (size_t)_v0 * HROW);           \
        const uint4* _h1 = (const uint4*)(hi_g + (size_t)_v1 * HROW);           \
        ha##S##0 = _h0[0]; hb##S##0 = _h0[1]; hc##S##0 = _h0[2];                \
        ha##S##1 = _h1[0]; hb##S##1 = _h1[1]; hc##S##1 = _h1[2];                \
        dg##S##0 = deg[_v0]; dg##S##1 = deg[_v1]; } } while (0)

#define PROCB(S, BB) do { const int _pb = (BB);                                 \
    int _my0 = (_pb + lane < n) ? 0 : 2;                                        \
    int _my1 = (_pb + 64 + lane < n) ? 0 : 2;                                   \
    for (;;) {                                                                  \
        if (_my0 == 0) DECIDE(_my0, _pb + lane,      pd##S##0, ha##S##0, hb##S##0, hc##S##0, dg##S##0, _pb); \
        if (_my1 == 0) DECIDE(_my1, _pb + 64 + lane, pd##S##1, ha##S##1, hb##S##1, hc##S##1, dg##S##1, _pb); \
        if (__ballot((_my0 == 0) || (_my1 == 0)) == 0ULL) break;                \
    }                                                                           \
} while (0)

__global__ __launch_bounds__(64)
void k_mis(const int* __restrict__ nbr, const int* __restrict__ deg,
           int maxdeg, int n,
           const uint2* __restrict__ pend_g, const unsigned short* __restrict__ hi_g,
           int* __restrict__ headlist, float* __restrict__ out_tail)
{
    __shared__ __align__(16) unsigned char st[NV];
    const int lane = threadIdx.x;    // 0..63, single wave

    #pragma unroll
    for (int i = 0; i < 16; ++i)
        ((uint4*)st)[lane + 64 * i] = make_uint4(0u, 0u, 0u, 0u);

    DECLB(A) DECLB(B) DECLB(C)
    LOADB(A, 0);
    LOADB(B, MBLK);
    for (int b = 0; b < n; b += 3 * MBLK) {
        LOADB(C, b + 2 * MBLK);
        PROCB(A, b);
        if (b + MBLK >= n) break;
        LOADB(A, b + 3 * MBLK);
        PROCB(B, b + MBLK);
        if (b + 2 * MBLK >= n) break;
        LOADB(B, b + 4 * MBLK);
        PROCB(C, b + 2 * MBLK);
    }

    // ---- epilogue: count heads, wave scan, emit headlist / head_mask / count
    // lane owns bytes [lane*256, lane*256+256)
    int cnt = 0;
    #pragma unroll
    for (int i = 0; i < 16; ++i) {
        uint4 q = ((const uint4*)st)[lane * 16 + i];
        cnt += __popc(q.x & 0x01010101u) + __popc(q.y & 0x01010101u)
             + __popc(q.z & 0x01010101u) + __popc(q.w & 0x01010101u);
    }
    int c = cnt;
    #pragma unroll
    for (int off = 1; off < 64; off <<= 1) {
        int x = __shfl_up(c, off);
        if (lane >= off) c += x;
    }
    const int tot  = __shfl(c, 63);
    int excl = c - cnt;
    for (int i = 0; i < 256; ++i) {
        int v = lane * 256 + i;
        if (st[v] == 1) { headlist[excl] = v; ++excl; }
    }
    // head_mask floats, coalesced float4 stores (byte==1 -> 1.0f)
    for (int i = lane; i < NV / 4; i += 64) {
        unsigned w = ((const unsigned*)st)[i];
        float4 f;
        f.x = (float)(w & 1u);         f.y = (float)((w >> 8) & 1u);
        f.z = (float)((w >> 16) & 1u); f.w = (float)((w >> 24) & 1u);
        ((float4*)out_tail)[i] = f;
    }
    if (lane == 0) out_tail[n] = (float)tot;
}

// ---------------------------------------------------------------------------
// K_owner: 16 lanes per vertex. owner[v] = v if head else min head neighbor.
// ---------------------------------------------------------------------------
__global__ __launch_bounds__(256)
void k_owner(const int* __restrict__ nbr, const int* __restrict__ deg,
             int maxdeg, int n,
             const float* __restrict__ hm, int* __restrict__ owner)
{
    int gid = blockIdx.x * 256 + threadIdx.x;
    int v = gid >> 4, l = gid & 15;
    if (v >= n) return;
    if (hm[v] != 0.0f) { if (l == 0) owner[v] = v; return; }
    const int* __restrict__ row = nbr + (size_t)v * (size_t)maxdeg;
    const int dv = deg[v];
    int mn = 0x7fffffff;
    for (int k = l; k < dv; k += 16) {
        int j = row[k];
        if (hm[j] != 0.0f) mn = min(mn, j);
    }
    #pragma unroll
    for (int off = 8; off; off >>= 1) mn = min(mn, __shfl_xor(mn, off, 16));
    if (l == 0) owner[v] = mn;
}

// ---------------------------------------------------------------------------
// K_avg: one 64-lane wave per output row. Waves [0,tot): cluster mean for
// headlist[w]. Waves [tot,n): zero-fill the row (replaces the memset).
// ---------------------------------------------------------------------------
__global__ __launch_bounds__(256)
void k_avg(const float* __restrict__ vert, const int* __restrict__ nbr,
           const int* __restrict__ deg, int maxdeg, int n,
           const int* __restrict__ headlist, const int* __restrict__ owner,
           const float* __restrict__ tail, float* __restrict__ out)
{
    const int w    = (blockIdx.x * 256 + threadIdx.x) >> 6;
    const int lane = threadIdx.x & 63;
    if (w >= n) return;
    const int tot  = (int)tail[n];
    if (w >= tot) {
        reinterpret_cast<float4*>(out + (size_t)w * DD)[lane] = make_float4(0.f, 0.f, 0.f, 0.f);
        return;
    }
    const int h = headlist[w];

    const int dh = deg[h];
    const int* __restrict__ row = nbr + (size_t)h * (size_t)maxdeg;

    float4 acc = reinterpret_cast<const float4*>(vert + (size_t)h * DD)[lane];
    int cnt = 1;

    for (int k0 = 0; k0 < dh; k0 += 64) {
        int k = k0 + lane;
        int j = (k < dh) ? row[k] : -1;
        bool mem = (j >= 0) && (owner[j] == h);
        unsigned long long m = __ballot(mem);
        cnt += __popcll(m);
        while (m) {
            int bit = __ffsll((long long)m) - 1;
            m &= (m - 1);
            int jj = __shfl(j, bit);
            float4 rr = reinterpret_cast<const float4*>(vert + (size_t)jj * DD)[lane];
            acc.x += rr.x; acc.y += rr.y; acc.z += rr.z; acc.w += rr.w;
        }
    }
    const float inv = 1.0f / (float)cnt;
    float4 res;
    res.x = acc.x * inv; res.y = acc.y * inv;
    res.z = acc.z * inv; res.w = acc.w * inv;
    reinterpret_cast<float4*>(out + (size_t)w * DD)[lane] = res;
}

// ---------------------------------------------------------------------------
extern "C" void kernel_launch(void* const* d_in, const int* in_sizes, int n_in,
                              void* d_out, int out_size, void* d_ws, size_t ws_size,
                              hipStream_t stream)
{
    const float* vert = (const float*)d_in[0];
    const int*   nbr  = (const int*)d_in[1];
    const int*   deg  = (const int*)d_in[2];

    const int n      = in_sizes[2];            // 16384
    const int maxdeg = in_sizes[1] / n;
    const int d      = in_sizes[0] / n;        // 256

    int*   owner    = (int*)d_ws;                                  // n ints
    int*   headlist = owner + n;                                   // n ints
    uint2* pend_g   = (uint2*)(headlist + n);                      // n uint2 (8B)
    unsigned short* hi_g = (unsigned short*)(pend_g + n);          // n * HROW u16

    float* out      = (float*)d_out;
    float* out_tail = out + (size_t)n * (size_t)d;   // head_mask .. num_clusters

    hipLaunchKernelGGL(k_prep, dim3((n + 255) / 256), dim3(256), 0, stream,
                       nbr, deg, maxdeg, n, pend_g, hi_g);

    hipLaunchKernelGGL(k_mis, dim3(1), dim3(64), 0, stream,
                       nbr, deg, maxdeg, n, pend_g, hi_g, headlist, out_tail);

    hipLaunchKernelGGL(k_owner, dim3((n * 16 + 255) / 256), dim3(256), 0, stream,
                       nbr, deg, maxdeg, n, out_tail, owner);

    const int blocks = (n * 64 + 255) / 256;   // one wave per output row
    hipLaunchKernelGGL(k_avg, dim3(blocks), dim3(256), 0, stream,
                       vert, nbr, deg, maxdeg, n, headlist, owner, out_tail, out);
}

// Round 7
// 234.075 us; speedup vs baseline: 1.5041x; 1.5041x over previous
//
#include <hip/hip_runtime.h>
#include <cstdint>
#include <cstddef>

// Problem constants (from reference): N=16384, D=256.
#define NV 16384
#define DD 256
#define TPB 512            // k_mis threads (8 waves)
#define BLK 512            // == TPB, one vertex per thread per block
#define PCAP 15
#define NPASS 4

// ---------------------------------------------------------------------------
// K_prep (parallel): per vertex v, collect ALL lower neighbors (j < v) as u16
// global ids, capped at 15, packed into two uint4:
//   a.x = count | e0<<16 ; a.y = e1|e2<<16 ; a.z = e3|e4<<16 ; a.w = e5|e6<<16
//   b.x = e7|e8<<16 ; b.y = e9|e10<<16 ; b.z = e11|e12<<16 ; b.w = e13|e14<<16
// Pure PULL model: k_mis decides each vertex solely from these statuses.
// ---------------------------------------------------------------------------
__global__ __launch_bounds__(256)
void k_prep(const int* __restrict__ nbr, const int* __restrict__ deg,
            int maxdeg, int n, uint4* __restrict__ pend_g)
{
    int v = blockIdx.x * 256 + threadIdx.x;
    if (v >= n) return;
    const int dv = deg[v];
    const int* __restrict__ row = nbr + (size_t)v * (size_t)maxdeg;
    unsigned ax = 0, ay = 0, az = 0, aw = 0, bx = 0, by = 0, bz = 0, bw = 0;
    int cnt = 0;
    for (int k = 0; k < dv; ++k) {
        int j = row[k];
        if (j < v) {
            unsigned e = (unsigned)j;
            switch (cnt) {
                case 0:  ax |= e << 16; break;
                case 1:  ay |= e;       break;
                case 2:  ay |= e << 16; break;
                case 3:  az |= e;       break;
                case 4:  az |= e << 16; break;
                case 5:  aw |= e;       break;
                case 6:  aw |= e << 16; break;
                case 7:  bx |= e;       break;
                case 8:  bx |= e << 16; break;
                case 9:  by |= e;       break;
                case 10: by |= e << 16; break;
                case 11: bz |= e;       break;
                case 12: bz |= e << 16; break;
                case 13: bw |= e;       break;
                case 14: bw |= e << 16; break;
                default: break;
            }
            ++cnt;
        }
    }
    ax |= (unsigned)(cnt > 0xffff ? 0xffff : cnt);
    uint4 A; A.x = ax; A.y = ay; A.z = az; A.w = aw;
    uint4 B; B.x = bx; B.y = by; B.z = bz; B.w = bw;
    pend_g[2 * (size_t)v]     = A;
    pend_g[2 * (size_t)v + 1] = B;
}

// ---------------------------------------------------------------------------
// K_mis: lexicographic greedy MIS, single WG of 512 threads (8 waves), PULL.
// st: 0=unknown, 1=head, 2=nonhead in LDS (monotone; races benign).
// Block b..b+511: each thread owns one vertex; per round, up to NPASS probe
// passes over its register-resident pend list (<=15 independent LDS byte
// reads), with per-wave ballot early-exit. 1 barrier per round via 3-slot F.
// All pend entries < b are final (earlier blocks), in-block ones resolve
// within passes (chain depth per 512-block ~3-4). No pushes, no hi-lists.
// ---------------------------------------------------------------------------
#define PRB(E, K) { int q = st[(E)]; if ((K) < np) { anyH |= (q == 1); undec += (q == 0); } }

__global__ __launch_bounds__(TPB)
void k_mis(const int* __restrict__ nbr, const int* __restrict__ deg,
           int maxdeg, int n, const uint4* __restrict__ pend_g,
           int* __restrict__ headlist, float* __restrict__ out_tail)
{
    __shared__ __align__(16) unsigned char st[NV];
    __shared__ int s_ws[TPB / 64];
    __shared__ int F[3];
    const int t    = threadIdx.x;
    const int lane = t & 63;
    const int wid  = t >> 6;

    #pragma unroll
    for (int i = 0; i < NV / 16 / TPB; ++i)
        ((uint4*)st)[t + TPB * i] = make_uint4(0u, 0u, 0u, 0u);
    if (t < 3) F[t] = 0;
    __syncthreads();

    // prefetch block 0, double-buffered across blocks
    uint4 pa = make_uint4(0,0,0,0), pb = pa;
    if (t < n) { pa = pend_g[2 * (size_t)t]; pb = pend_g[2 * (size_t)t + 1]; }
    int r = 0;

    for (int b = 0; b < n; b += BLK) {
        uint4 qa = make_uint4(0,0,0,0), qb = qa;
        {
            int vn = b + BLK + t;
            if (vn < n) { qa = pend_g[2 * (size_t)vn]; qb = pend_g[2 * (size_t)vn + 1]; }
        }

        const int v  = b + t;
        const int np = (int)(pa.x & 0xffffu);
        int my = (v < n) ? 0 : 2;
        int dvf = 0;
        if (my == 0 && np > PCAP) dvf = deg[v];   // rare overflow needs deg

        for (;; ++r) {
            if (t == 0) F[(r + 1) % 3] = 0;
            for (int pass = 0; pass < NPASS; ++pass) {
                if (my == 0) {
                    bool anyH = false; int undec = 0;
                    if (np <= PCAP) {
                        PRB(pa.x >> 16,      0)
                        PRB(pa.y & 0xffffu,  1)  PRB(pa.y >> 16,  2)
                        PRB(pa.z & 0xffffu,  3)  PRB(pa.z >> 16,  4)
                        PRB(pa.w & 0xffffu,  5)  PRB(pa.w >> 16,  6)
                        PRB(pb.x & 0xffffu,  7)  PRB(pb.x >> 16,  8)
                        PRB(pb.y & 0xffffu,  9)  PRB(pb.y >> 16, 10)
                        PRB(pb.z & 0xffffu, 11)  PRB(pb.z >> 16, 12)
                        PRB(pb.w & 0xffffu, 13)  PRB(pb.w >> 16, 14)
                    } else {
                        const int* __restrict__ row = nbr + (size_t)v * (size_t)maxdeg;
                        for (int k = 0; k < dvf; ++k) {
                            int j = row[k];
                            if (j < v) { int q = st[j]; anyH |= (q == 1); undec += (q == 0); }
                        }
                    }
                    if (anyH)            { my = 2; st[v] = 2; }
                    else if (undec == 0) { my = 1; st[v] = 1; }
                }
                if (__ballot(my == 0) == 0ULL) break;   // wave-local early out
            }
            if (my == 0) F[r % 3] = 1;
            __syncthreads();
            if (F[r % 3] == 0) { ++r; break; }
        }
        pa = qa; pb = qb;
    }

    // ---- epilogue: count heads, scan, emit headlist / head_mask / count ----
    // thread t owns bytes [32t, 32t+32)
    int cnt = 0;
    #pragma unroll
    for (int i = 0; i < 2; ++i) {
        uint4 q = ((const uint4*)st)[t * 2 + i];
        cnt += __popc(q.x & 0x01010101u) + __popc(q.y & 0x01010101u)
             + __popc(q.z & 0x01010101u) + __popc(q.w & 0x01010101u);
    }
    int c = cnt;
    #pragma unroll
    for (int off = 1; off < 64; off <<= 1) {
        int x = __shfl_up(c, off);
        if (lane >= off) c += x;
    }
    if (lane == 63) s_ws[wid] = c;
    __syncthreads();
    int wexcl = 0, tot = 0;
    #pragma unroll
    for (int w = 0; w < TPB / 64; ++w) {
        int s = s_ws[w];
        tot += s;
        if (w < wid) wexcl += s;
    }
    int excl = wexcl + (c - cnt);
    for (int i = 0; i < 32; ++i) {
        int v = t * 32 + i;
        if (st[v] == 1) { headlist[excl] = v; ++excl; }
    }
    // head_mask floats, coalesced float4 stores (byte==1 -> 1.0f)
    for (int i = t; i < NV / 4; i += TPB) {
        unsigned w = ((const unsigned*)st)[i];
        float4 f;
        f.x = (float)(w & 1u);         f.y = (float)((w >> 8) & 1u);
        f.z = (float)((w >> 16) & 1u); f.w = (float)((w >> 24) & 1u);
        ((float4*)out_tail)[i] = f;
    }
    if (t == 0) out_tail[n] = (float)tot;
}

// ---------------------------------------------------------------------------
// K_owner: 16 lanes per vertex. owner[v] = v if head else min head neighbor.
// ---------------------------------------------------------------------------
__global__ __launch_bounds__(256)
void k_owner(const int* __restrict__ nbr, const int* __restrict__ deg,
             int maxdeg, int n,
             const float* __restrict__ hm, int* __restrict__ owner)
{
    int gid = blockIdx.x * 256 + threadIdx.x;
    int v = gid >> 4, l = gid & 15;
    if (v >= n) return;
    if (hm[v] != 0.0f) { if (l == 0) owner[v] = v; return; }
    const int* __restrict__ row = nbr + (size_t)v * (size_t)maxdeg;
    const int dv = deg[v];
    int mn = 0x7fffffff;
    for (int k = l; k < dv; k += 16) {
        int j = row[k];
        if (hm[j] != 0.0f) mn = min(mn, j);
    }
    #pragma unroll
    for (int off = 8; off; off >>= 1) mn = min(mn, __shfl_xor(mn, off, 16));
    if (l == 0) owner[v] = mn;
}

// ---------------------------------------------------------------------------
// K_avg: one 64-lane wave per output row. Waves [0,tot): cluster mean for
// headlist[w]. Waves [tot,n): zero-fill the row (replaces the memset).
// ---------------------------------------------------------------------------
__global__ __launch_bounds__(256)
void k_avg(const float* __restrict__ vert, const int* __restrict__ nbr,
           const int* __restrict__ deg, int maxdeg, int n,
           const int* __restrict__ headlist, const int* __restrict__ owner,
           const float* __restrict__ tail, float* __restrict__ out)
{
    const int w    = (blockIdx.x * 256 + threadIdx.x) >> 6;
    const int lane = threadIdx.x & 63;
    if (w >= n) return;
    const int tot  = (int)tail[n];
    if (w >= tot) {
        reinterpret_cast<float4*>(out + (size_t)w * DD)[lane] = make_float4(0.f, 0.f, 0.f, 0.f);
        return;
    }
    const int h = headlist[w];

    const int dh = deg[h];
    const int* __restrict__ row = nbr + (size_t)h * (size_t)maxdeg;

    float4 acc = reinterpret_cast<const float4*>(vert + (size_t)h * DD)[lane];
    int cnt = 1;

    for (int k0 = 0; k0 < dh; k0 += 64) {
        int k = k0 + lane;
        int j = (k < dh) ? row[k] : -1;
        bool mem = (j >= 0) && (owner[j] == h);
        unsigned long long m = __ballot(mem);
        cnt += __popcll(m);
        while (m) {
            int bit = __ffsll((long long)m) - 1;
            m &= (m - 1);
            int jj = __shfl(j, bit);
            float4 rr = reinterpret_cast<const float4*>(vert + (size_t)jj * DD)[lane];
            acc.x += rr.x; acc.y += rr.y; acc.z += rr.z; acc.w += rr.w;
        }
    }
    const float inv = 1.0f / (float)cnt;
    float4 res;
    res.x = acc.x * inv; res.y = acc.y * inv;
    res.z = acc.z * inv; res.w = acc.w * inv;
    reinterpret_cast<float4*>(out + (size_t)w * DD)[lane] = res;
}

// ---------------------------------------------------------------------------
extern "C" void kernel_launch(void* const* d_in, const int* in_sizes, int n_in,
                              void* d_out, int out_size, void* d_ws, size_t ws_size,
                              hipStream_t stream)
{
    const float* vert = (const float*)d_in[0];
    const int*   nbr  = (const int*)d_in[1];
    const int*   deg  = (const int*)d_in[2];

    const int n      = in_sizes[2];            // 16384
    const int maxdeg = in_sizes[1] / n;
    const int d      = in_sizes[0] / n;        // 256

    int*   owner    = (int*)d_ws;                                  // n ints
    int*   headlist = owner + n;                                   // n ints
    uint4* pend_g   = (uint4*)(headlist + n);                      // 2n uint4 (16B-aligned: 2n ints = 128KB)

    float* out      = (float*)d_out;
    float* out_tail = out + (size_t)n * (size_t)d;   // head_mask .. num_clusters

    hipLaunchKernelGGL(k_prep, dim3((n + 255) / 256), dim3(256), 0, stream,
                       nbr, deg, maxdeg, n, pend_g);

    hipLaunchKernelGGL(k_mis, dim3(1), dim3(TPB), 0, stream,
                       nbr, deg, maxdeg, n, pend_g, headlist, out_tail);

    hipLaunchKernelGGL(k_owner, dim3((n * 16 + 255) / 256), dim3(256), 0, stream,
                       nbr, deg, maxdeg, n, out_tail, owner);

    const int blocks = (n * 64 + 255) / 256;   // one wave per output row
    hipLaunchKernelGGL(k_avg, dim3(blocks), dim3(256), 0, stream,
                       vert, nbr, deg, maxdeg, n, headlist, owner, out_tail, out);
}

// Round 8
// 182.364 us; speedup vs baseline: 1.9306x; 1.2836x over previous
//
#include <hip/hip_runtime.h>
#include <cstdint>
#include <cstddef>

// Problem constants (from reference): N=16384, D=256.
#define NV 16384
#define DD 256
#define TPB 1024           // k_mis threads (16 waves)
#define BLK 1024           // == TPB, one vertex per thread per block
#define PCAP 15
#define NPASS 3

// ---------------------------------------------------------------------------
// K_prep (parallel): per vertex v, collect ALL lower neighbors (j < v) as u16
// global ids, capped at 15, packed into two uint4:
//   a.x = count | e0<<16 ; a.y = e1|e2<<16 ; a.z = e3|e4<<16 ; a.w = e5|e6<<16
//   b.x = e7|e8<<16 ; ... ; b.w = e13|e14<<16
// ---------------------------------------------------------------------------
__global__ __launch_bounds__(256)
void k_prep(const int* __restrict__ nbr, const int* __restrict__ deg,
            int maxdeg, int n, uint4* __restrict__ pend_g)
{
    int v = blockIdx.x * 256 + threadIdx.x;
    if (v >= n) return;
    const int dv = deg[v];
    const int* __restrict__ row = nbr + (size_t)v * (size_t)maxdeg;
    unsigned ax = 0, ay = 0, az = 0, aw = 0, bx = 0, by = 0, bz = 0, bw = 0;
    int cnt = 0;
    for (int k = 0; k < dv; ++k) {
        int j = row[k];
        if (j < v) {
            unsigned e = (unsigned)j;
            switch (cnt) {
                case 0:  ax |= e << 16; break;
                case 1:  ay |= e;       break;
                case 2:  ay |= e << 16; break;
                case 3:  az |= e;       break;
                case 4:  az |= e << 16; break;
                case 5:  aw |= e;       break;
                case 6:  aw |= e << 16; break;
                case 7:  bx |= e;       break;
                case 8:  bx |= e << 16; break;
                case 9:  by |= e;       break;
                case 10: by |= e << 16; break;
                case 11: bz |= e;       break;
                case 12: bz |= e << 16; break;
                case 13: bw |= e;       break;
                case 14: bw |= e << 16; break;
                default: break;
            }
            ++cnt;
        }
    }
    ax |= (unsigned)(cnt > 0xffff ? 0xffff : cnt);
    uint4 A; A.x = ax; A.y = ay; A.z = az; A.w = aw;
    uint4 B; B.x = bx; B.y = by; B.z = bz; B.w = bw;
    pend_g[2 * (size_t)v]     = A;
    pend_g[2 * (size_t)v + 1] = B;
}

// ---------------------------------------------------------------------------
// K_mis: lexicographic greedy MIS, single WG of 1024 threads (16 waves), PULL.
// st: 0=unknown, 1=head, 2=nonhead in LDS (each vertex writes ONLY its own
// byte -> no write races). Per block of 1024 vertices (1/thread):
//   - each pass loads all 15 pend statuses into NAMED temps first (independent
//     ds_read_u8 batch, single wait), then folds: anyHead + unresolved mask.
//   - prev-block entries are final -> resolve on pass 0; in-block chains
//     resolve across passes/rounds (monotone LDS visibility intra-WG).
//   - NPASS passes per barrier, per-wave ballot early-exit, 3-slot F flag.
// ---------------------------------------------------------------------------
__global__ __launch_bounds__(TPB)
void k_mis(const int* __restrict__ nbr, const int* __restrict__ deg,
           int maxdeg, int n, const uint4* __restrict__ pend_g,
           int* __restrict__ headlist, float* __restrict__ out_tail)
{
    __shared__ __align__(16) unsigned char st[NV];
    __shared__ int s_ws[TPB / 64];
    __shared__ int F[3];
    const int t    = threadIdx.x;
    const int lane = t & 63;
    const int wid  = t >> 6;

    ((uint4*)st)[t] = make_uint4(0u, 0u, 0u, 0u);   // 1024 * 16B == NV
    if (t < 3) F[t] = 0;
    __syncthreads();

    // prefetch block 0, double-buffered across blocks
    uint4 pa = make_uint4(0,0,0,0), pb = pa;
    if (t < n) { pa = pend_g[2 * (size_t)t]; pb = pend_g[2 * (size_t)t + 1]; }
    int r = 0;

    for (int b = 0; b < n; b += BLK) {
        uint4 qa = make_uint4(0,0,0,0), qb = qa;
        {
            int vn = b + BLK + t;
            if (vn < n) { qa = pend_g[2 * (size_t)vn]; qb = pend_g[2 * (size_t)vn + 1]; }
        }

        const int v  = b + t;
        const int np = (int)(pa.x & 0xffffu);
        const bool ovf = (np > PCAP);
        const int e0 = pa.x >> 16,      e1 = pa.y & 0xffff, e2 = pa.y >> 16;
        const int e3 = pa.z & 0xffff,   e4 = pa.z >> 16;
        const int e5 = pa.w & 0xffff,   e6 = pa.w >> 16;
        const int e7 = pb.x & 0xffff,   e8 = pb.x >> 16;
        const int e9 = pb.y & 0xffff,   e10 = pb.y >> 16;
        const int e11 = pb.z & 0xffff,  e12 = pb.z >> 16;
        const int e13 = pb.w & 0xffff,  e14 = pb.w >> 16;

        unsigned mask = ovf ? 0u : ((np >= 15) ? 0x7fffu : ((1u << np) - 1u));
        bool anyH = false;
        int  my   = (v < n) ? 0 : 2;
        int  dvf  = 0;
        if (my == 0 && ovf) dvf = deg[v];   // rare (>15 lower nbrs): global row

        for (;; ++r) {
            if (t == 0) F[(r + 1) % 3] = 0;
            #pragma unroll
            for (int pass = 0; pass < NPASS; ++pass) {
                if (my == 0) {
                    if (!ovf) {
                        // batched independent probes (named temps -> one wait)
                        int q0 = st[e0],  q1 = st[e1],  q2 = st[e2],  q3 = st[e3];
                        int q4 = st[e4],  q5 = st[e5],  q6 = st[e6],  q7 = st[e7];
                        int q8 = st[e8],  q9 = st[e9],  q10 = st[e10], q11 = st[e11];
                        int q12 = st[e12], q13 = st[e13], q14 = st[e14];
                        #define FOLD(K, QK) if (mask & (1u << (K))) { anyH |= ((QK) == 1); if (QK) mask &= ~(1u << (K)); }
                        FOLD(0, q0)  FOLD(1, q1)  FOLD(2, q2)  FOLD(3, q3)
                        FOLD(4, q4)  FOLD(5, q5)  FOLD(6, q6)  FOLD(7, q7)
                        FOLD(8, q8)  FOLD(9, q9)  FOLD(10, q10) FOLD(11, q11)
                        FOLD(12, q12) FOLD(13, q13) FOLD(14, q14)
                        #undef FOLD
                    } else {
                        const int* __restrict__ row = nbr + (size_t)v * (size_t)maxdeg;
                        int undec = 0;
                        for (int k = 0; k < dvf; ++k) {
                            int j = row[k];
                            if (j < v) { int q = st[j]; anyH |= (q == 1); undec += (q == 0); }
                        }
                        mask = undec ? 1u : 0u;
                    }
                    if (anyH)           { my = 2; st[v] = 2; }
                    else if (mask == 0) { my = 1; st[v] = 1; }
                }
                if (__ballot(my == 0) == 0ULL) break;   // wave-local early out
            }
            if (my == 0) F[r % 3] = 1;
            __syncthreads();
            if (F[r % 3] == 0) { ++r; break; }
        }
        pa = qa; pb = qb;
    }

    // ---- epilogue: count heads, scan, emit headlist / head_mask / count ----
    // thread t owns bytes [16t, 16t+16)
    uint4 qq = ((const uint4*)st)[t];
    int cnt = __popc(qq.x & 0x01010101u) + __popc(qq.y & 0x01010101u)
            + __popc(qq.z & 0x01010101u) + __popc(qq.w & 0x01010101u);
    int c = cnt;
    #pragma unroll
    for (int off = 1; off < 64; off <<= 1) {
        int x = __shfl_up(c, off);
        if (lane >= off) c += x;
    }
    if (lane == 63) s_ws[wid] = c;
    __syncthreads();
    int wexcl = 0, tot = 0;
    #pragma unroll
    for (int w = 0; w < TPB / 64; ++w) {
        int s = s_ws[w];
        tot += s;
        if (w < wid) wexcl += s;
    }
    int excl = wexcl + (c - cnt);
    #pragma unroll
    for (int i = 0; i < 16; ++i) {
        int v = t * 16 + i;
        if (st[v] == 1) { headlist[excl] = v; ++excl; }
    }
    // head_mask floats, coalesced float4 stores (byte==1 -> 1.0f)
    for (int i = t; i < NV / 4; i += TPB) {
        unsigned w = ((const unsigned*)st)[i];
        float4 f;
        f.x = (float)(w & 1u);         f.y = (float)((w >> 8) & 1u);
        f.z = (float)((w >> 16) & 1u); f.w = (float)((w >> 24) & 1u);
        ((float4*)out_tail)[i] = f;
    }
    if (t == 0) out_tail[n] = (float)tot;
}

// ---------------------------------------------------------------------------
// K_owner: 16 lanes per vertex. owner[v] = v if head else min head neighbor.
// ---------------------------------------------------------------------------
__global__ __launch_bounds__(256)
void k_owner(const int* __restrict__ nbr, const int* __restrict__ deg,
             int maxdeg, int n,
             const float* __restrict__ hm, int* __restrict__ owner)
{
    int gid = blockIdx.x * 256 + threadIdx.x;
    int v = gid >> 4, l = gid & 15;
    if (v >= n) return;
    if (hm[v] != 0.0f) { if (l == 0) owner[v] = v; return; }
    const int* __restrict__ row = nbr + (size_t)v * (size_t)maxdeg;
    const int dv = deg[v];
    int mn = 0x7fffffff;
    for (int k = l; k < dv; k += 16) {
        int j = row[k];
        if (hm[j] != 0.0f) mn = min(mn, j);
    }
    #pragma unroll
    for (int off = 8; off; off >>= 1) mn = min(mn, __shfl_xor(mn, off, 16));
    if (l == 0) owner[v] = mn;
}

// ---------------------------------------------------------------------------
// K_avg: one 64-lane wave per output row. Waves [0,tot): cluster mean for
// headlist[w]. Waves [tot,n): zero-fill the row (replaces the memset).
// ---------------------------------------------------------------------------
__global__ __launch_bounds__(256)
void k_avg(const float* __restrict__ vert, const int* __restrict__ nbr,
           const int* __restrict__ deg, int maxdeg, int n,
           const int* __restrict__ headlist, const int* __restrict__ owner,
           const float* __restrict__ tail, float* __restrict__ out)
{
    const int w    = (blockIdx.x * 256 + threadIdx.x) >> 6;
    const int lane = threadIdx.x & 63;
    if (w >= n) return;
    const int tot  = (int)tail[n];
    if (w >= tot) {
        reinterpret_cast<float4*>(out + (size_t)w * DD)[lane] = make_float4(0.f, 0.f, 0.f, 0.f);
        return;
    }
    const int h = headlist[w];

    const int dh = deg[h];
    const int* __restrict__ row = nbr + (size_t)h * (size_t)maxdeg;

    float4 acc = reinterpret_cast<const float4*>(vert + (size_t)h * DD)[lane];
    int cnt = 1;

    for (int k0 = 0; k0 < dh; k0 += 64) {
        int k = k0 + lane;
        int j = (k < dh) ? row[k] : -1;
        bool mem = (j >= 0) && (owner[j] == h);
        unsigned long long m = __ballot(mem);
        cnt += __popcll(m);
        while (m) {
            int bit = __ffsll((long long)m) - 1;
            m &= (m - 1);
            int jj = __shfl(j, bit);
            float4 rr = reinterpret_cast<const float4*>(vert + (size_t)jj * DD)[lane];
            acc.x += rr.x; acc.y += rr.y; acc.z += rr.z; acc.w += rr.w;
        }
    }
    const float inv = 1.0f / (float)cnt;
    float4 res;
    res.x = acc.x * inv; res.y = acc.y * inv;
    res.z = acc.z * inv; res.w = acc.w * inv;
    reinterpret_cast<float4*>(out + (size_t)w * DD)[lane] = res;
}

// ---------------------------------------------------------------------------
extern "C" void kernel_launch(void* const* d_in, const int* in_sizes, int n_in,
                              void* d_out, int out_size, void* d_ws, size_t ws_size,
                              hipStream_t stream)
{
    const float* vert = (const float*)d_in[0];
    const int*   nbr  = (const int*)d_in[1];
    const int*   deg  = (const int*)d_in[2];

    const int n      = in_sizes[2];            // 16384
    const int maxdeg = in_sizes[1] / n;
    const int d      = in_sizes[0] / n;        // 256

    int*   owner    = (int*)d_ws;                                  // n ints
    int*   headlist = owner + n;                                   // n ints
    uint4* pend_g   = (uint4*)(headlist + n);                      // 2n uint4

    float* out      = (float*)d_out;
    float* out_tail = out + (size_t)n * (size_t)d;   // head_mask .. num_clusters

    hipLaunchKernelGGL(k_prep, dim3((n + 255) / 256), dim3(256), 0, stream,
                       nbr, deg, maxdeg, n, pend_g);

    hipLaunchKernelGGL(k_mis, dim3(1), dim3(TPB), 0, stream,
                       nbr, deg, maxdeg, n, pend_g, headlist, out_tail);

    hipLaunchKernelGGL(k_owner, dim3((n * 16 + 255) / 256), dim3(256), 0, stream,
                       nbr, deg, maxdeg, n, out_tail, owner);

    const int blocks = (n * 64 + 255) / 256;   // one wave per output row
    hipLaunchKernelGGL(k_avg, dim3(blocks), dim3(256), 0, stream,
                       vert, nbr, deg, maxdeg, n, headlist, owner, out_tail, out);
}